// Round 1
// 760.964 us; speedup vs baseline: 1.1953x; 1.1953x over previous
//
#include <hip/hip_runtime.h>
#include <hip/hip_fp16.h>

#define TDIM 2048
#define BDIM 4
#define MROWS 8192   // B*T
#define NDIM 2048
#define KDIM 2048
#define NH 16

typedef __attribute__((ext_vector_type(8))) _Float16 f16x8;
typedef __attribute__((ext_vector_type(4))) _Float16 f16x4;
typedef __attribute__((ext_vector_type(4))) float f32x4;

__device__ __forceinline__ void load16_to_lds(const _Float16* g, _Float16* l) {
  __builtin_amdgcn_global_load_lds((const __attribute__((address_space(1))) void*)g,
                                   (__attribute__((address_space(3))) void*)l,
                                   16, 0, 0);
}

// counted-vmcnt barrier: NEVER drain vmcnt(0) in the main loop (T4).
// raw s_barrier (NOT __syncthreads -> would emit vmcnt(0)).
// sched_barrier(0) pins the backend from hoisting next-iter ds_reads
// above the barrier (rule 18 analog).
#define WAITBAR(N) do { \
  asm volatile("s_waitcnt vmcnt(" #N ")" ::: "memory"); \
  __builtin_amdgcn_s_barrier(); \
  __builtin_amdgcn_sched_barrier(0); \
} while (0)

// ---------------- pass 1: fp32 -> fp16 conversion ----------------
__global__ __launch_bounds__(256) void cvt6_kernel(
    const float* __restrict__ s0, const float* __restrict__ s1,
    const float* __restrict__ s2, const float* __restrict__ s3,
    const float* __restrict__ s4, const float* __restrict__ s5,
    _Float16* __restrict__ d0, _Float16* __restrict__ d1,
    _Float16* __restrict__ d2, _Float16* __restrict__ d3,
    _Float16* __restrict__ d4, _Float16* __restrict__ d5) {
  const int z = blockIdx.z;
  const float* s; _Float16* d; int n;
  switch (z) {
    case 0: s = s0; d = d0; n = MROWS * KDIM; break;
    case 1: s = s1; d = d1; n = MROWS * KDIM; break;
    case 2: s = s2; d = d2; n = MROWS * KDIM; break;
    case 3: s = s3; d = d3; n = NDIM * KDIM; break;
    case 4: s = s4; d = d4; n = NDIM * KDIM; break;
    default: s = s5; d = d5; n = NDIM * KDIM; break;
  }
  const int n4 = n >> 2;
  const int stride = gridDim.x * blockDim.x;
  for (int i = blockIdx.x * blockDim.x + threadIdx.x; i < n4; i += stride) {
    float4 f = ((const float4*)s)[i];
    f16x4 h;
    h.x = (_Float16)f.x; h.y = (_Float16)f.y;
    h.z = (_Float16)f.z; h.w = (_Float16)f.w;
    ((f16x4*)d)[i] = h;
  }
}

// ---------------- pass 2: fp16 MFMA GEMM ----------------
// 256x256 tile, BK=32, 512 threads = 8 waves (2M x 4N), per-wave 128x64.
// 4-slot LDS ring buffer (128 KiB), staging 3 K-tiles ahead with
// global_load_lds + counted vmcnt(8) across raw barriers (T3+T4),
// XOR-swizzled LDS (T2-equivalent, provably conflict-free for the
// ds_read_b128 fragment pattern), setprio around MFMA cluster (T5),
// bijective XCD blockIdx swizzle (T1).
__global__ __launch_bounds__(512, 2) void gemm_kernel(
    const _Float16* __restrict__ A0, const _Float16* __restrict__ A1,
    const _Float16* __restrict__ A2,
    const _Float16* __restrict__ W0, const _Float16* __restrict__ W1,
    const _Float16* __restrict__ W2,
    _Float16* __restrict__ qraw, _Float16* __restrict__ kraw,
    float* __restrict__ vout) {
  // [buf 0..3][A=0/B=1][256 rows x 32 halves] = 128 KiB
  __shared__ __align__(16) _Float16 lds[4][2][8192];

  // XCD-aware bijective swizzle: grid = 8*32*3 = 768 = 8 XCDs * 96
  int lin = (blockIdx.z * gridDim.y + blockIdx.y) * gridDim.x + blockIdx.x;
  lin = (lin & 7) * 96 + (lin >> 3);
  const int z  = lin >> 8;         // 0..2
  const int ty = (lin >> 3) & 31;  // m-tile 0..31
  const int tx = lin & 7;          // n-tile 0..7

  const _Float16* __restrict__ A  = (z == 0) ? A0 : ((z == 1) ? A1 : A2);
  const _Float16* __restrict__ Wt = (z == 0) ? W0 : ((z == 1) ? W1 : W2);
  const int m0 = ty * 256;
  const int n0 = tx * 256;

  const int tid  = threadIdx.x;
  const int wave = tid >> 6;
  const int lane = tid & 63;
  const int m_in = lane & 15;
  const int kq   = lane >> 4;
  const int wave_m = wave >> 2;  // 0..1 -> A rows wave_m*128
  const int wave_n = wave & 3;   // 0..3 -> B cols wave_n*64

  f32x4 acc[8][4];
  const f32x4 z4 = {0.f, 0.f, 0.f, 0.f};
#pragma unroll
  for (int i = 0; i < 8; ++i)
#pragma unroll
    for (int j = 0; j < 4; ++j) acc[i][j] = z4;

  // ---- staging addresses (pre-swizzled global source, linear LDS dest) ----
  // phys chunk P (bytes) -> logical L = P ^ (((P>>7)&3)<<4)  (involution,
  // touches bits 4-5 only; row bits >=6 preserved). row = L>>6 (64B rows),
  // k halves = (L&63)>>1.
  const int P0 = tid * 16;
  const int P1 = (512 + tid) * 16;
  const int L0 = P0 ^ (((P0 >> 7) & 3) << 4);
  const int L1 = P1 ^ (((P1 >> 7) & 3) << 4);
  const _Float16* srcA0 = A  + (size_t)(m0 + (L0 >> 6)) * KDIM + ((L0 & 63) >> 1);
  const _Float16* srcA1 = A  + (size_t)(m0 + (L1 >> 6)) * KDIM + ((L1 & 63) >> 1);
  const _Float16* srcB0 = Wt + (size_t)(n0 + (L0 >> 6)) * KDIM + ((L0 & 63) >> 1);
  const _Float16* srcB1 = Wt + (size_t)(n0 + (L1 >> 6)) * KDIM + ((L1 & 63) >> 1);
  const int dst0 = (wave * 64) * 8;        // halves; lane*16B appended by HW
  const int dst1 = (512 + wave * 64) * 8;

  // ---- fragment LDS byte offsets (same swizzle on the read side) ----
  // slot(8 lanes consecutive) = ((row&1)<<2) | (kq ^ ((row>>1)&3)) -> all 8
  // distinct => conflict-free ds_read_b128.
  int offA[8], offB[4];
#pragma unroll
  for (int mi = 0; mi < 8; ++mi) {
    const int r = wave_m * 128 + mi * 16 + m_in;
    offA[mi] = r * 64 + ((kq ^ ((r >> 1) & 3)) << 4);
  }
#pragma unroll
  for (int ni = 0; ni < 4; ++ni) {
    const int r = wave_n * 64 + ni * 16 + m_in;
    offB[ni] = r * 64 + ((kq ^ ((r >> 1) & 3)) << 4);
  }

  auto stage = [&](int kt) {  // 4 gload_lds per thread (A:2, B:2)
    _Float16* base = &lds[kt & 3][0][0];
    const int ko = kt * 32;
    load16_to_lds(srcA0 + ko, base + dst0);
    load16_to_lds(srcA1 + ko, base + dst1);
    load16_to_lds(srcB0 + ko, base + 8192 + dst0);
    load16_to_lds(srcB1 + ko, base + 8192 + dst1);
  };

  auto compute = [&](int kt) {  // 12 ds_read_b128 + 32 MFMA
    const char* Ab = (const char*)&lds[kt & 3][0][0];
    const char* Bb = (const char*)&lds[kt & 3][1][0];
    f16x8 a[8], b[4];
#pragma unroll
    for (int mi = 0; mi < 8; ++mi) a[mi] = *(const f16x8*)(Ab + offA[mi]);
#pragma unroll
    for (int ni = 0; ni < 4; ++ni) b[ni] = *(const f16x8*)(Bb + offB[ni]);
    __builtin_amdgcn_s_setprio(1);
#pragma unroll
    for (int mi = 0; mi < 8; ++mi)
#pragma unroll
      for (int ni = 0; ni < 4; ++ni)
        acc[mi][ni] = __builtin_amdgcn_mfma_f32_16x16x32_f16(a[mi], b[ni], acc[mi][ni], 0, 0, 0);
    __builtin_amdgcn_s_setprio(0);
  };

  // prologue: tiles 0,1,2 in flight (12 loads); drain tile 0 (8 remain)
  stage(0); stage(1); stage(2);
  WAITBAR(8);

  // steady state: stage kt+3, compute kt, drain tile kt+1 (keep 8 in flight)
#pragma unroll 1
  for (int kt = 0; kt < KDIM / 32 - 3; ++kt) {
    stage(kt + 3);
    compute(kt);
    WAITBAR(8);
  }
  compute(KDIM / 32 - 3); WAITBAR(4);   // drain tile 62
  compute(KDIM / 32 - 2); WAITBAR(0);   // drain tile 63
  compute(KDIM / 32 - 1);               // ring empty; no barrier needed

  // ---- epilogue: C/D layout col=lane&15, row=(lane>>4)*4+reg ----
  const int rbase = kq * 4;
  const int wm = wave_m * 128;
  const int wn = wave_n * 64;
  if (z < 2) {
    _Float16* __restrict__ raw = (z == 0) ? qraw : kraw;
#pragma unroll
    for (int mi = 0; mi < 8; ++mi) {
      const int m = m0 + wm + mi * 16 + rbase;
#pragma unroll
      for (int ni = 0; ni < 4; ++ni) {
        const int n = n0 + wn + ni * 16 + m_in;
#pragma unroll
        for (int r = 0; r < 4; ++r)
          raw[(size_t)(m + r) * NDIM + n] = (_Float16)acc[mi][ni][r];
      }
    }
  } else {
#pragma unroll
    for (int mi = 0; mi < 8; ++mi) {
      const int mb = m0 + wm + mi * 16 + rbase;
#pragma unroll
      for (int ni = 0; ni < 4; ++ni) {
        const int n = n0 + wn + ni * 16 + m_in;
        const int h = n >> 7, dd = n & 127;
#pragma unroll
        for (int r = 0; r < 4; ++r) {
          const int m = mb + r;
          const int b = m >> 11, t = m & 2047;
          vout[(((size_t)(b * NH + h) * TDIM) + t) * 128 + dd] = acc[mi][ni][r];
        }
      }
    }
  }
}

// ---------------- pass 3: concat + LayerNorm + head-split + RoPE ----------------
__global__ __launch_bounds__(256) void ln_rope_kernel(
    const _Float16* __restrict__ qraw, const _Float16* __restrict__ kraw,
    const float* __restrict__ negator,
    const float* __restrict__ q_gamma, const float* __restrict__ q_beta,
    const float* __restrict__ k_gamma, const float* __restrict__ k_beta,
    const int* __restrict__ offset_p,
    float* __restrict__ out) {
  const int row = blockIdx.x;   // b*T + t
  const int mat = blockIdx.y;   // 0: q, 1: k
  const _Float16* __restrict__ raw = mat ? kraw : qraw;
  const float* __restrict__ gamma = mat ? k_gamma : q_gamma;
  const float* __restrict__ beta  = mat ? k_beta  : q_beta;
  float* __restrict__ outb = out + (size_t)mat * ((size_t)BDIM * NH * TDIM * 256);

  const float c = negator[0];
  const float mu = 0.5f * c;
  const int tid = threadIdx.x;

  __shared__ __align__(16) float vals[2048];
  __shared__ float wred[4];

  const int b = row >> 11, t = row & 2047;
  const float tpos = (float)(t + offset_p[0]);
  const int d = tid;

  float sv = 0.f, cv = 0.f;
  if (d < 128) {
    const int p = d >> 1;
    const float invf = exp2f(-(float)p * 0.20762050592854797f); // log2(1e4)/64
    sincosf(tpos * invf, &sv, &cv);
  }

  f16x8 hv = ((const f16x8*)(raw + (size_t)row * 2048))[tid];
  float v[8];
  float ss = 0.f;
#pragma unroll
  for (int j = 0; j < 8; ++j) {
    float x = (float)hv[j] - mu;
    v[j] = x;
    ss += x * x;
  }
  ((float4*)vals)[tid * 2 + 0] = make_float4(v[0], v[1], v[2], v[3]);
  ((float4*)vals)[tid * 2 + 1] = make_float4(v[4], v[5], v[6], v[7]);

#pragma unroll
  for (int o = 32; o > 0; o >>= 1) ss += __shfl_down(ss, o, 64);
  if ((tid & 63) == 0) wred[tid >> 6] = ss;
  __syncthreads();
  const float var = (wred[0] + wred[1] + wred[2] + wred[3]) * (1.0f / 2048.0f);
  const float rstd = rsqrtf(var + 1e-5f);

#pragma unroll
  for (int i = 0; i < 16; ++i) {
    const int g = i * 256 + tid;
    const float sgn = (g < 2048) ? 1.f : -1.f;
    const float y = sgn * vals[g & 2047] * rstd * gamma[g] + beta[g];
    float res;
    if (d < 128) {
      const int gp = g ^ 1;
      const float yp = sgn * vals[gp & 2047] * rstd * gamma[gp] + beta[gp];
      res = (d & 1) ? (y * cv + yp * sv) : (y * cv - yp * sv);
    } else {
      res = y;
    }
    outb[(((size_t)(b * NH + i) * TDIM) + t) * 256 + d] = res;
  }
}

extern "C" void kernel_launch(void* const* d_in, const int* in_sizes, int n_in,
                              void* d_out, int out_size, void* d_ws, size_t ws_size,
                              hipStream_t stream) {
  (void)in_sizes; (void)n_in; (void)out_size; (void)ws_size;
  const float* q_state = (const float*)d_in[0];
  const float* k_state = (const float*)d_in[1];
  const float* v_state = (const float*)d_in[2];
  const float* Wq = (const float*)d_in[3];
  const float* Wk = (const float*)d_in[4];
  const float* Wv = (const float*)d_in[5];
  const float* negator = (const float*)d_in[6];
  const float* q_gamma = (const float*)d_in[7];
  const float* q_beta  = (const float*)d_in[8];
  const float* k_gamma = (const float*)d_in[9];
  const float* k_beta  = (const float*)d_in[10];
  const int* offset    = (const int*)d_in[11];

  float* out = (float*)d_out;
  float* vout = out + (size_t)2 * BDIM * NH * TDIM * 256;

  _Float16* Aq   = (_Float16*)d_ws;
  _Float16* Ak   = Aq + (size_t)MROWS * KDIM;
  _Float16* Av   = Ak + (size_t)MROWS * KDIM;
  _Float16* Wq16 = Av + (size_t)MROWS * KDIM;
  _Float16* Wk16 = Wq16 + (size_t)NDIM * KDIM;
  _Float16* Wv16 = Wk16 + (size_t)NDIM * KDIM;
  _Float16* qraw = Wv16 + (size_t)NDIM * KDIM;
  _Float16* kraw = qraw + (size_t)MROWS * NDIM;

  cvt6_kernel<<<dim3(2048, 1, 6), dim3(256), 0, stream>>>(
      q_state, k_state, v_state, Wq, Wk, Wv, Aq, Ak, Av, Wq16, Wk16, Wv16);

  gemm_kernel<<<dim3(8, 32, 3), dim3(512), 0, stream>>>(
      Aq, Ak, Av, Wq16, Wk16, Wv16, qraw, kraw, vout);

  ln_rope_kernel<<<dim3(8192, 2), dim3(256), 0, stream>>>(
      qraw, kraw, negator, q_gamma, q_beta, k_gamma, k_beta, offset, out);
}

// Round 2
// 744.838 us; speedup vs baseline: 1.2212x; 1.0216x over previous
//
#include <hip/hip_runtime.h>
#include <hip/hip_fp16.h>

#define TDIM 2048
#define BDIM 4
#define MROWS 8192   // B*T
#define NDIM 2048
#define KDIM 2048
#define NH 16

typedef __attribute__((ext_vector_type(8))) _Float16 f16x8;
typedef __attribute__((ext_vector_type(4))) _Float16 f16x4;
typedef __attribute__((ext_vector_type(4))) float f32x4;

__device__ __forceinline__ void load16_to_lds(const _Float16* g, _Float16* l) {
  __builtin_amdgcn_global_load_lds((const __attribute__((address_space(1))) void*)g,
                                   (__attribute__((address_space(3))) void*)l,
                                   16, 0, 0);
}

// counted-vmcnt barrier: NEVER drain vmcnt(0) in the main loop (T4).
#define WAITBAR(N) do { \
  asm volatile("s_waitcnt vmcnt(" #N ")" ::: "memory"); \
  __builtin_amdgcn_s_barrier(); \
  __builtin_amdgcn_sched_barrier(0); \
} while (0)

// ---------------- pass 1: fp32 -> fp16 conversion (16B stores) ----------------
__global__ __launch_bounds__(256) void cvt6_kernel(
    const float* __restrict__ s0, const float* __restrict__ s1,
    const float* __restrict__ s2, const float* __restrict__ s3,
    const float* __restrict__ s4, const float* __restrict__ s5,
    _Float16* __restrict__ d0, _Float16* __restrict__ d1,
    _Float16* __restrict__ d2, _Float16* __restrict__ d3,
    _Float16* __restrict__ d4, _Float16* __restrict__ d5) {
  const int z = blockIdx.z;
  const float* s; _Float16* d; int n;
  switch (z) {
    case 0: s = s0; d = d0; n = MROWS * KDIM; break;
    case 1: s = s1; d = d1; n = MROWS * KDIM; break;
    case 2: s = s2; d = d2; n = MROWS * KDIM; break;
    case 3: s = s3; d = d3; n = NDIM * KDIM; break;
    case 4: s = s4; d = d4; n = NDIM * KDIM; break;
    default: s = s5; d = d5; n = NDIM * KDIM; break;
  }
  const int n8 = n >> 3;  // all sizes divisible by 8
  const int stride = gridDim.x * blockDim.x;
  for (int i = blockIdx.x * blockDim.x + threadIdx.x; i < n8; i += stride) {
    float4 f0 = ((const float4*)s)[i * 2 + 0];
    float4 f1 = ((const float4*)s)[i * 2 + 1];
    f16x8 h;
    h[0] = (_Float16)f0.x; h[1] = (_Float16)f0.y;
    h[2] = (_Float16)f0.z; h[3] = (_Float16)f0.w;
    h[4] = (_Float16)f1.x; h[5] = (_Float16)f1.y;
    h[6] = (_Float16)f1.z; h[7] = (_Float16)f1.w;
    ((f16x8*)d)[i] = h;
  }
}

// ---------------- rope table: [t][p]{cos,sin}, p = 0..63 ----------------
__global__ __launch_bounds__(256) void rope_fill_kernel(
    const int* __restrict__ offset_p, float* __restrict__ tab) {
  const int idx = blockIdx.x * blockDim.x + threadIdx.x;  // t*64 + p
  if (idx >= TDIM * 64) return;
  const int t = idx >> 6, p = idx & 63;
  const float tpos = (float)(t + offset_p[0]);
  const float invf = exp2f(-(float)p * 0.20762050592854797f);  // log2(1e4)/64
  float sv, cv;
  sincosf(tpos * invf, &sv, &cv);
  tab[idx * 2 + 0] = cv;
  tab[idx * 2 + 1] = sv;
}

// ---------------- pass 2: fp16 MFMA GEMM (unchanged, verified) ----------------
__global__ __launch_bounds__(512, 2) void gemm_kernel(
    const _Float16* __restrict__ A0, const _Float16* __restrict__ A1,
    const _Float16* __restrict__ A2,
    const _Float16* __restrict__ W0, const _Float16* __restrict__ W1,
    const _Float16* __restrict__ W2,
    _Float16* __restrict__ qraw, _Float16* __restrict__ kraw,
    float* __restrict__ vout) {
  __shared__ __align__(16) _Float16 lds[4][2][8192];

  // XCD-aware bijective swizzle: grid = 8*32*3 = 768 = 8 XCDs * 96
  int lin = (blockIdx.z * gridDim.y + blockIdx.y) * gridDim.x + blockIdx.x;
  lin = (lin & 7) * 96 + (lin >> 3);
  const int z  = lin >> 8;
  const int ty = (lin >> 3) & 31;
  const int tx = lin & 7;

  const _Float16* __restrict__ A  = (z == 0) ? A0 : ((z == 1) ? A1 : A2);
  const _Float16* __restrict__ Wt = (z == 0) ? W0 : ((z == 1) ? W1 : W2);
  const int m0 = ty * 256;
  const int n0 = tx * 256;

  const int tid  = threadIdx.x;
  const int wave = tid >> 6;
  const int lane = tid & 63;
  const int m_in = lane & 15;
  const int kq   = lane >> 4;
  const int wave_m = wave >> 2;
  const int wave_n = wave & 3;

  f32x4 acc[8][4];
  const f32x4 z4 = {0.f, 0.f, 0.f, 0.f};
#pragma unroll
  for (int i = 0; i < 8; ++i)
#pragma unroll
    for (int j = 0; j < 4; ++j) acc[i][j] = z4;

  // phys chunk P -> logical L = P ^ (((P>>7)&3)<<4) (involution, bits 4-5)
  const int P0 = tid * 16;
  const int P1 = (512 + tid) * 16;
  const int L0 = P0 ^ (((P0 >> 7) & 3) << 4);
  const int L1 = P1 ^ (((P1 >> 7) & 3) << 4);
  const _Float16* srcA0 = A  + (size_t)(m0 + (L0 >> 6)) * KDIM + ((L0 & 63) >> 1);
  const _Float16* srcA1 = A  + (size_t)(m0 + (L1 >> 6)) * KDIM + ((L1 & 63) >> 1);
  const _Float16* srcB0 = Wt + (size_t)(n0 + (L0 >> 6)) * KDIM + ((L0 & 63) >> 1);
  const _Float16* srcB1 = Wt + (size_t)(n0 + (L1 >> 6)) * KDIM + ((L1 & 63) >> 1);
  const int dst0 = (wave * 64) * 8;
  const int dst1 = (512 + wave * 64) * 8;

  int offA[8], offB[4];
#pragma unroll
  for (int mi = 0; mi < 8; ++mi) {
    const int r = wave_m * 128 + mi * 16 + m_in;
    offA[mi] = r * 64 + ((kq ^ ((r >> 1) & 3)) << 4);
  }
#pragma unroll
  for (int ni = 0; ni < 4; ++ni) {
    const int r = wave_n * 64 + ni * 16 + m_in;
    offB[ni] = r * 64 + ((kq ^ ((r >> 1) & 3)) << 4);
  }

  auto stage = [&](int kt) {
    _Float16* base = &lds[kt & 3][0][0];
    const int ko = kt * 32;
    load16_to_lds(srcA0 + ko, base + dst0);
    load16_to_lds(srcA1 + ko, base + dst1);
    load16_to_lds(srcB0 + ko, base + 8192 + dst0);
    load16_to_lds(srcB1 + ko, base + 8192 + dst1);
  };

  auto compute = [&](int kt) {
    const char* Ab = (const char*)&lds[kt & 3][0][0];
    const char* Bb = (const char*)&lds[kt & 3][1][0];
    f16x8 a[8], b[4];
#pragma unroll
    for (int mi = 0; mi < 8; ++mi) a[mi] = *(const f16x8*)(Ab + offA[mi]);
#pragma unroll
    for (int ni = 0; ni < 4; ++ni) b[ni] = *(const f16x8*)(Bb + offB[ni]);
    __builtin_amdgcn_s_setprio(1);
#pragma unroll
    for (int mi = 0; mi < 8; ++mi)
#pragma unroll
      for (int ni = 0; ni < 4; ++ni)
        acc[mi][ni] = __builtin_amdgcn_mfma_f32_16x16x32_f16(a[mi], b[ni], acc[mi][ni], 0, 0, 0);
    __builtin_amdgcn_s_setprio(0);
  };

  stage(0); stage(1); stage(2);
  WAITBAR(8);

#pragma unroll 1
  for (int kt = 0; kt < KDIM / 32 - 3; ++kt) {
    stage(kt + 3);
    compute(kt);
    WAITBAR(8);
  }
  compute(KDIM / 32 - 3); WAITBAR(4);
  compute(KDIM / 32 - 2); WAITBAR(0);
  compute(KDIM / 32 - 1);

  const int rbase = kq * 4;
  const int wm = wave_m * 128;
  const int wn = wave_n * 64;
  if (z < 2) {
    _Float16* __restrict__ raw = (z == 0) ? qraw : kraw;
#pragma unroll
    for (int mi = 0; mi < 8; ++mi) {
      const int m = m0 + wm + mi * 16 + rbase;
#pragma unroll
      for (int ni = 0; ni < 4; ++ni) {
        const int n = n0 + wn + ni * 16 + m_in;
#pragma unroll
        for (int r = 0; r < 4; ++r)
          raw[(size_t)(m + r) * NDIM + n] = (_Float16)acc[mi][ni][r];
      }
    }
  } else {
#pragma unroll
    for (int mi = 0; mi < 8; ++mi) {
      const int mb = m0 + wm + mi * 16 + rbase;
#pragma unroll
      for (int ni = 0; ni < 4; ++ni) {
        const int n = n0 + wn + ni * 16 + m_in;
        const int h = n >> 7, dd = n & 127;
#pragma unroll
        for (int r = 0; r < 4; ++r) {
          const int m = mb + r;
          const int b = m >> 11, t = m & 2047;
          vout[(((size_t)(b * NH + h) * TDIM) + t) * 128 + dd] = acc[mi][ni][r];
        }
      }
    }
  }
}

// ---------------- pass 3: concat + LayerNorm + head-split + RoPE ----------------
// Thread owns 4 CONSECUTIVE output channels -> float4 (16B) stores, RoPE pairs
// thread-local (no partner LDS read), cos/sin from precomputed table (float4).
__global__ __launch_bounds__(256) void ln_rope_kernel(
    const _Float16* __restrict__ qraw, const _Float16* __restrict__ kraw,
    const float* __restrict__ negator,
    const float* __restrict__ q_gamma, const float* __restrict__ q_beta,
    const float* __restrict__ k_gamma, const float* __restrict__ k_beta,
    const float* __restrict__ rope_tab,
    float* __restrict__ out) {
  const int row = blockIdx.x;   // b*T + t
  const int mat = blockIdx.y;   // 0: q, 1: k
  const _Float16* __restrict__ raw = mat ? kraw : qraw;
  const float* __restrict__ gamma = mat ? k_gamma : q_gamma;
  const float* __restrict__ beta  = mat ? k_beta  : q_beta;
  float* __restrict__ outb = out + (size_t)mat * ((size_t)BDIM * NH * TDIM * 256);

  const float c = negator[0];
  const float mu = 0.5f * c;
  const int tid = threadIdx.x;

  __shared__ __align__(16) float vals[2048];
  __shared__ float wred[4];

  const int b = row >> 11, t = row & 2047;

  // phase 1: load row (fp16), center, partial sum of squares, stage to LDS
  f16x8 hv = ((const f16x8*)(raw + (size_t)row * 2048))[tid];
  float v[8];
  float ss = 0.f;
#pragma unroll
  for (int j = 0; j < 8; ++j) {
    float x = (float)hv[j] - mu;
    v[j] = x;
    ss += x * x;
  }
  ((float4*)vals)[tid * 2 + 0] = make_float4(v[0], v[1], v[2], v[3]);
  ((float4*)vals)[tid * 2 + 1] = make_float4(v[4], v[5], v[6], v[7]);

#pragma unroll
  for (int o = 32; o > 0; o >>= 1) ss += __shfl_down(ss, o, 64);
  if ((tid & 63) == 0) wred[tid >> 6] = ss;
  __syncthreads();
  const float var = (wred[0] + wred[1] + wred[2] + wred[3]) * (1.0f / 2048.0f);
  const float rstd = rsqrtf(var + 1e-5f);

  const float4* __restrict__ tab4 = (const float4*)(rope_tab + (size_t)t * 128);

  // phase 2: 4 iterations, 4 consecutive channels per thread
#pragma unroll
  for (int j = 0; j < 4; ++j) {
    const int g0 = j * 1024 + tid * 4;          // output channel base (4-aligned)
    const float sgn = (g0 < 2048) ? 1.f : -1.f;
    const float4 val = ((const float4*)vals)[(g0 & 2047) >> 2];
    const float4 gm  = ((const float4*)gamma)[g0 >> 2];
    const float4 bt  = ((const float4*)beta)[g0 >> 2];
    float y0 = sgn * val.x * rstd * gm.x + bt.x;
    float y1 = sgn * val.y * rstd * gm.y + bt.y;
    float y2 = sgn * val.z * rstd * gm.z + bt.z;
    float y3 = sgn * val.w * rstd * gm.w + bt.w;

    const int h  = g0 >> 8;        // head
    const int d0 = g0 & 255;       // within-head channel base
    float4 res;
    if (d0 < 128) {
      // cs = (cos_p, sin_p, cos_{p+1}, sin_{p+1}), p = d0>>1 (even)
      const float4 cs = tab4[d0 >> 2];
      res.x = y0 * cs.x - y1 * cs.y;
      res.y = y1 * cs.x + y0 * cs.y;
      res.z = y2 * cs.z - y3 * cs.w;
      res.w = y3 * cs.z + y2 * cs.w;
    } else {
      res = make_float4(y0, y1, y2, y3);
    }
    ((float4*)(outb + (((size_t)(b * NH + h) * TDIM) + t) * 256))[d0 >> 2] = res;
  }
}

extern "C" void kernel_launch(void* const* d_in, const int* in_sizes, int n_in,
                              void* d_out, int out_size, void* d_ws, size_t ws_size,
                              hipStream_t stream) {
  (void)in_sizes; (void)n_in; (void)out_size; (void)ws_size;
  const float* q_state = (const float*)d_in[0];
  const float* k_state = (const float*)d_in[1];
  const float* v_state = (const float*)d_in[2];
  const float* Wq = (const float*)d_in[3];
  const float* Wk = (const float*)d_in[4];
  const float* Wv = (const float*)d_in[5];
  const float* negator = (const float*)d_in[6];
  const float* q_gamma = (const float*)d_in[7];
  const float* q_beta  = (const float*)d_in[8];
  const float* k_gamma = (const float*)d_in[9];
  const float* k_beta  = (const float*)d_in[10];
  const int* offset    = (const int*)d_in[11];

  float* out = (float*)d_out;
  float* vout = out + (size_t)2 * BDIM * NH * TDIM * 256;

  _Float16* Aq   = (_Float16*)d_ws;
  _Float16* Ak   = Aq + (size_t)MROWS * KDIM;
  _Float16* Av   = Ak + (size_t)MROWS * KDIM;
  _Float16* Wq16 = Av + (size_t)MROWS * KDIM;
  _Float16* Wk16 = Wq16 + (size_t)NDIM * KDIM;
  _Float16* Wv16 = Wk16 + (size_t)NDIM * KDIM;
  _Float16* qraw = Wv16 + (size_t)NDIM * KDIM;
  _Float16* kraw = qraw + (size_t)MROWS * NDIM;

  // rope table (1 MiB) aliases Wq16 (8 MiB, dead after gemm): no ws growth
  float* rope_tab = (float*)Wq16;

  cvt6_kernel<<<dim3(2048, 1, 6), dim3(256), 0, stream>>>(
      q_state, k_state, v_state, Wq, Wk, Wv, Aq, Ak, Av, Wq16, Wk16, Wv16);

  gemm_kernel<<<dim3(8, 32, 3), dim3(512), 0, stream>>>(
      Aq, Ak, Av, Wq16, Wk16, Wv16, qraw, kraw, vout);

  rope_fill_kernel<<<dim3(512), dim3(256), 0, stream>>>(offset, rope_tab);

  ln_rope_kernel<<<dim3(8192, 2), dim3(256), 0, stream>>>(
      qraw, kraw, negator, q_gamma, q_beta, k_gamma, k_beta, rope_tab, out);
}

// Round 4
// 735.397 us; speedup vs baseline: 1.2369x; 1.0128x over previous
//
#include <hip/hip_runtime.h>
#include <hip/hip_fp16.h>

#define TDIM 2048
#define BDIM 4
#define MROWS 8192   // B*T
#define NDIM 2048
#define KDIM 2048
#define NH 16

typedef __attribute__((ext_vector_type(8))) _Float16 f16x8;
typedef __attribute__((ext_vector_type(4))) _Float16 f16x4;
typedef __attribute__((ext_vector_type(4))) float f32x4;

__device__ __forceinline__ void load16_to_lds(const _Float16* g, _Float16* l) {
  __builtin_amdgcn_global_load_lds((const __attribute__((address_space(1))) void*)g,
                                   (__attribute__((address_space(3))) void*)l,
                                   16, 0, 0);
}

// counted-vmcnt barrier: NEVER drain vmcnt(0) in the main loop (T4).
#define WAITBAR(N) do { \
  asm volatile("s_waitcnt vmcnt(" #N ")" ::: "memory"); \
  __builtin_amdgcn_s_barrier(); \
  __builtin_amdgcn_sched_barrier(0); \
} while (0)

#define LGKM0_FENCE() do { \
  asm volatile("s_waitcnt lgkmcnt(0)" ::: "memory"); \
  __builtin_amdgcn_sched_barrier(0); \
} while (0)

// ---------------- pass 1: fp32 -> fp16 conversion + rope table ----------------
__global__ __launch_bounds__(256) void cvt7_kernel(
    const float* __restrict__ s0, const float* __restrict__ s1,
    const float* __restrict__ s2, const float* __restrict__ s3,
    const float* __restrict__ s4, const float* __restrict__ s5,
    _Float16* __restrict__ d0, _Float16* __restrict__ d1,
    _Float16* __restrict__ d2, _Float16* __restrict__ d3,
    _Float16* __restrict__ d4, _Float16* __restrict__ d5,
    const int* __restrict__ offset_p, float* __restrict__ rope_tab) {
  const int z = blockIdx.z;
  if (z == 6) {
    // rope table: [t][p]{cos,sin}, p = 0..63
    const int idx = blockIdx.x * blockDim.x + threadIdx.x;
    if (idx < TDIM * 64) {
      const int t = idx >> 6, p = idx & 63;
      const float tpos = (float)(t + offset_p[0]);
      const float invf = exp2f(-(float)p * 0.20762050592854797f);  // log2(1e4)/64
      float sv, cv;
      sincosf(tpos * invf, &sv, &cv);
      rope_tab[idx * 2 + 0] = cv;
      rope_tab[idx * 2 + 1] = sv;
    }
    return;
  }
  const float* s; _Float16* d; int n;
  switch (z) {
    case 0: s = s0; d = d0; n = MROWS * KDIM; break;
    case 1: s = s1; d = d1; n = MROWS * KDIM; break;
    case 2: s = s2; d = d2; n = MROWS * KDIM; break;
    case 3: s = s3; d = d3; n = NDIM * KDIM; break;
    case 4: s = s4; d = d4; n = NDIM * KDIM; break;
    default: s = s5; d = d5; n = NDIM * KDIM; break;
  }
  const int n8 = n >> 3;
  const int stride = gridDim.x * blockDim.x;
  for (int i = blockIdx.x * blockDim.x + threadIdx.x; i < n8; i += stride) {
    float4 f0 = ((const float4*)s)[i * 2 + 0];
    float4 f1 = ((const float4*)s)[i * 2 + 1];
    f16x8 h;
    h[0] = (_Float16)f0.x; h[1] = (_Float16)f0.y;
    h[2] = (_Float16)f0.z; h[3] = (_Float16)f0.w;
    h[4] = (_Float16)f1.x; h[5] = (_Float16)f1.y;
    h[6] = (_Float16)f1.z; h[7] = (_Float16)f1.w;
    ((f16x8*)d)[i] = h;
  }
}

// ---------------- pass 2: fp16 MFMA GEMM ----------------
// 256x256 tile, BK=32, 8 waves (2Mx4N), per-wave 128x64. 4-slot LDS ring,
// counted vmcnt(8) across raw barriers (T3+T4), XOR-swizzled LDS (T2),
// setprio (T5), XCD swizzle (T1). 2-phase K-step (reads+stage+16 MFMA per
// phase, mid-barrier) to overlap LDS reads with MFMA across waves;
// LDS-staged wide C-stores for q/k.
__global__ __launch_bounds__(512, 2) void gemm_kernel(
    const _Float16* __restrict__ A0, const _Float16* __restrict__ A1,
    const _Float16* __restrict__ A2,
    const _Float16* __restrict__ W0, const _Float16* __restrict__ W1,
    const _Float16* __restrict__ W2,
    _Float16* __restrict__ qraw, _Float16* __restrict__ kraw,
    float* __restrict__ vout) {
  __shared__ __align__(16) _Float16 lds[4][2][8192];

  // XCD-aware bijective swizzle: grid = 8*32*3 = 768 = 8 XCDs * 96
  int lin = (blockIdx.z * gridDim.y + blockIdx.y) * gridDim.x + blockIdx.x;
  lin = (lin & 7) * 96 + (lin >> 3);
  const int z  = lin >> 8;
  const int ty = (lin >> 3) & 31;
  const int tx = lin & 7;

  const _Float16* __restrict__ A  = (z == 0) ? A0 : ((z == 1) ? A1 : A2);
  const _Float16* __restrict__ Wt = (z == 0) ? W0 : ((z == 1) ? W1 : W2);
  const int m0 = ty * 256;
  const int n0 = tx * 256;

  const int tid  = threadIdx.x;
  const int wave = tid >> 6;
  const int lane = tid & 63;
  const int m_in = lane & 15;
  const int kq   = lane >> 4;
  const int wave_m = wave >> 2;
  const int wave_n = wave & 3;

  f32x4 acc[8][4];
  const f32x4 z4 = {0.f, 0.f, 0.f, 0.f};
#pragma unroll
  for (int i = 0; i < 8; ++i)
#pragma unroll
    for (int j = 0; j < 4; ++j) acc[i][j] = z4;

  // phys chunk P -> logical L = P ^ (((P>>7)&3)<<4) (involution, bits 4-5)
  const int P0 = tid * 16;
  const int P1 = (512 + tid) * 16;
  const int L0 = P0 ^ (((P0 >> 7) & 3) << 4);
  const int L1 = P1 ^ (((P1 >> 7) & 3) << 4);
  const _Float16* srcA0 = A  + (size_t)(m0 + (L0 >> 6)) * KDIM + ((L0 & 63) >> 1);
  const _Float16* srcA1 = A  + (size_t)(m0 + (L1 >> 6)) * KDIM + ((L1 & 63) >> 1);
  const _Float16* srcB0 = Wt + (size_t)(n0 + (L0 >> 6)) * KDIM + ((L0 & 63) >> 1);
  const _Float16* srcB1 = Wt + (size_t)(n0 + (L1 >> 6)) * KDIM + ((L1 & 63) >> 1);
  const int dst0 = (wave * 64) * 8;
  const int dst1 = (512 + wave * 64) * 8;

  int offA[8], offB[4];
#pragma unroll
  for (int mi = 0; mi < 8; ++mi) {
    const int r = wave_m * 128 + mi * 16 + m_in;
    offA[mi] = r * 64 + ((kq ^ ((r >> 1) & 3)) << 4);
  }
#pragma unroll
  for (int ni = 0; ni < 4; ++ni) {
    const int r = wave_n * 64 + ni * 16 + m_in;
    offB[ni] = r * 64 + ((kq ^ ((r >> 1) & 3)) << 4);
  }

  auto stageA = [&](int kt) {  // 2 gload_lds (A chunks)
    _Float16* base = &lds[kt & 3][0][0];
    const int ko = kt * 32;
    load16_to_lds(srcA0 + ko, base + dst0);
    load16_to_lds(srcA1 + ko, base + dst1);
  };
  auto stageB = [&](int kt) {  // 2 gload_lds (B chunks)
    _Float16* base = &lds[kt & 3][0][0];
    const int ko = kt * 32;
    load16_to_lds(srcB0 + ko, base + 8192 + dst0);
    load16_to_lds(srcB1 + ko, base + 8192 + dst1);
  };

  f16x8 a[8], b[4];

  // ---- 2-phase K-step body; stage_kt < 0 disables staging (tail) ----
  auto kstep_p1 = [&](int kt, int stage_kt) {
    const char* Ab = (const char*)&lds[kt & 3][0][0];
    const char* Bb = (const char*)&lds[kt & 3][1][0];
#pragma unroll
    for (int mi = 0; mi < 8; ++mi) a[mi] = *(const f16x8*)(Ab + offA[mi]);
    b[0] = *(const f16x8*)(Bb + offB[0]);
    b[1] = *(const f16x8*)(Bb + offB[1]);
    if (stage_kt >= 0) stageA(stage_kt);
    LGKM0_FENCE();
    __builtin_amdgcn_s_setprio(1);
#pragma unroll
    for (int mi = 0; mi < 8; ++mi)
#pragma unroll
      for (int ni = 0; ni < 2; ++ni)
        acc[mi][ni] = __builtin_amdgcn_mfma_f32_16x16x32_f16(a[mi], b[ni], acc[mi][ni], 0, 0, 0);
    __builtin_amdgcn_s_setprio(0);
    __builtin_amdgcn_s_barrier();
    __builtin_amdgcn_sched_barrier(0);
  };
  auto kstep_p2 = [&](int kt, int stage_kt) {
    const char* Bb = (const char*)&lds[kt & 3][1][0];
    b[2] = *(const f16x8*)(Bb + offB[2]);
    b[3] = *(const f16x8*)(Bb + offB[3]);
    if (stage_kt >= 0) stageB(stage_kt);
    LGKM0_FENCE();
    __builtin_amdgcn_s_setprio(1);
#pragma unroll
    for (int mi = 0; mi < 8; ++mi)
#pragma unroll
      for (int ni = 2; ni < 4; ++ni)
        acc[mi][ni] = __builtin_amdgcn_mfma_f32_16x16x32_f16(a[mi], b[ni], acc[mi][ni], 0, 0, 0);
    __builtin_amdgcn_s_setprio(0);
    // caller issues the iter-end WAITBAR
  };

  // prologue: tiles 0,1,2 in flight (12 loads); drain tile 0 (8 remain)
  stageA(0); stageB(0); stageA(1); stageB(1); stageA(2); stageB(2);
  WAITBAR(8);

  // steady state: per iter stage kt+3 (A in P1, B in P2), compute kt,
  // drain tile kt+1 at iter end (keep 8 loads in flight)
#pragma unroll 1
  for (int kt = 0; kt < KDIM / 32 - 3; ++kt) {
    kstep_p1(kt, kt + 3);
    kstep_p2(kt, kt + 3);
    WAITBAR(8);
  }
  kstep_p1(KDIM / 32 - 3, -1); kstep_p2(KDIM / 32 - 3, -1); WAITBAR(4);
  kstep_p1(KDIM / 32 - 2, -1); kstep_p2(KDIM / 32 - 2, -1); WAITBAR(0);
  kstep_p1(KDIM / 32 - 1, -1); kstep_p2(KDIM / 32 - 1, -1);

  // ---- epilogue: C/D layout col=lane&15, row=(lane>>4)*4+reg ----
  const int rbase = kq * 4;
  const int wm = wave_m * 128;
  const int wn = wave_n * 64;
  if (z < 2) {
    // stage C through LDS (reuse ring: 4*2*8192 halves = 256x256 tile),
    // then fully-coalesced f16x8 stores.
    _Float16* __restrict__ raw = (z == 0) ? qraw : kraw;
    _Float16* cst = &lds[0][0][0];
    __syncthreads();   // all K-loop LDS reads done before clobber
#pragma unroll
    for (int mi = 0; mi < 8; ++mi) {
      const int row = wm + mi * 16 + rbase;
#pragma unroll
      for (int ni = 0; ni < 4; ++ni) {
        const int col = wn + ni * 16 + m_in;
#pragma unroll
        for (int r = 0; r < 4; ++r)
          cst[(row + r) * 256 + col] = (_Float16)acc[mi][ni][r];
      }
    }
    __syncthreads();
#pragma unroll
    for (int j = 0; j < 16; ++j) {
      const int c = j * 512 + tid;          // 8192 chunks of 16B
      const int row = c >> 5, col8 = (c & 31) * 8;
      *(f16x8*)&raw[(size_t)(m0 + row) * NDIM + n0 + col8] =
          *(const f16x8*)&cst[row * 256 + col8];
    }
  } else {
#pragma unroll
    for (int mi = 0; mi < 8; ++mi) {
      const int mb = m0 + wm + mi * 16 + rbase;
#pragma unroll
      for (int ni = 0; ni < 4; ++ni) {
        const int n = n0 + wn + ni * 16 + m_in;
        const int h = n >> 7, dd = n & 127;
#pragma unroll
        for (int r = 0; r < 4; ++r) {
          const int m = mb + r;
          const int b = m >> 11, t = m & 2047;
          vout[(((size_t)(b * NH + h) * TDIM) + t) * 128 + dd] = acc[mi][ni][r];
        }
      }
    }
  }
}

// ---------------- pass 3: concat + LayerNorm + head-split + RoPE ----------------
__global__ __launch_bounds__(256) void ln_rope_kernel(
    const _Float16* __restrict__ qraw, const _Float16* __restrict__ kraw,
    const float* __restrict__ negator,
    const float* __restrict__ q_gamma, const float* __restrict__ q_beta,
    const float* __restrict__ k_gamma, const float* __restrict__ k_beta,
    const float* __restrict__ rope_tab,
    float* __restrict__ out) {
  const int row = blockIdx.x;   // b*T + t
  const int mat = blockIdx.y;   // 0: q, 1: k
  const _Float16* __restrict__ raw = mat ? kraw : qraw;
  const float* __restrict__ gamma = mat ? k_gamma : q_gamma;
  const float* __restrict__ beta  = mat ? k_beta  : q_beta;
  float* __restrict__ outb = out + (size_t)mat * ((size_t)BDIM * NH * TDIM * 256);

  const float c = negator[0];
  const float mu = 0.5f * c;
  const int tid = threadIdx.x;

  __shared__ __align__(16) float vals[2048];
  __shared__ float wred[4];

  const int b = row >> 11, t = row & 2047;

  f16x8 hv = ((const f16x8*)(raw + (size_t)row * 2048))[tid];
  float v[8];
  float ss = 0.f;
#pragma unroll
  for (int j = 0; j < 8; ++j) {
    float x = (float)hv[j] - mu;
    v[j] = x;
    ss += x * x;
  }
  ((float4*)vals)[tid * 2 + 0] = make_float4(v[0], v[1], v[2], v[3]);
  ((float4*)vals)[tid * 2 + 1] = make_float4(v[4], v[5], v[6], v[7]);

#pragma unroll
  for (int o = 32; o > 0; o >>= 1) ss += __shfl_down(ss, o, 64);
  if ((tid & 63) == 0) wred[tid >> 6] = ss;
  __syncthreads();
  const float var = (wred[0] + wred[1] + wred[2] + wred[3]) * (1.0f / 2048.0f);
  const float rstd = rsqrtf(var + 1e-5f);

  const float4* __restrict__ tab4 = (const float4*)(rope_tab + (size_t)t * 128);

#pragma unroll
  for (int j = 0; j < 4; ++j) {
    const int g0 = j * 1024 + tid * 4;
    const float sgn = (g0 < 2048) ? 1.f : -1.f;
    const float4 val = ((const float4*)vals)[(g0 & 2047) >> 2];
    const float4 gm  = ((const float4*)gamma)[g0 >> 2];
    const float4 bt  = ((const float4*)beta)[g0 >> 2];
    float y0 = sgn * val.x * rstd * gm.x + bt.x;
    float y1 = sgn * val.y * rstd * gm.y + bt.y;
    float y2 = sgn * val.z * rstd * gm.z + bt.z;
    float y3 = sgn * val.w * rstd * gm.w + bt.w;

    const int h  = g0 >> 8;
    const int d0 = g0 & 255;
    float4 res;
    if (d0 < 128) {
      const float4 cs = tab4[d0 >> 2];
      res.x = y0 * cs.x - y1 * cs.y;
      res.y = y1 * cs.x + y0 * cs.y;
      res.z = y2 * cs.z - y3 * cs.w;
      res.w = y3 * cs.z + y2 * cs.w;
    } else {
      res = make_float4(y0, y1, y2, y3);
    }
    ((float4*)(outb + (((size_t)(b * NH + h) * TDIM) + t) * 256))[d0 >> 2] = res;
  }
}

extern "C" void kernel_launch(void* const* d_in, const int* in_sizes, int n_in,
                              void* d_out, int out_size, void* d_ws, size_t ws_size,
                              hipStream_t stream) {
  (void)in_sizes; (void)n_in; (void)out_size; (void)ws_size;
  const float* q_state = (const float*)d_in[0];
  const float* k_state = (const float*)d_in[1];
  const float* v_state = (const float*)d_in[2];
  const float* Wq = (const float*)d_in[3];
  const float* Wk = (const float*)d_in[4];
  const float* Wv = (const float*)d_in[5];
  const float* negator = (const float*)d_in[6];
  const float* q_gamma = (const float*)d_in[7];
  const float* q_beta  = (const float*)d_in[8];
  const float* k_gamma = (const float*)d_in[9];
  const float* k_beta  = (const float*)d_in[10];
  const int* offset    = (const int*)d_in[11];

  float* out = (float*)d_out;
  float* vout = out + (size_t)2 * BDIM * NH * TDIM * 256;

  _Float16* Aq   = (_Float16*)d_ws;
  _Float16* Ak   = Aq + (size_t)MROWS * KDIM;
  _Float16* Av   = Ak + (size_t)MROWS * KDIM;
  _Float16* Wq16 = Av + (size_t)MROWS * KDIM;
  _Float16* Wk16 = Wq16 + (size_t)NDIM * KDIM;
  _Float16* Wv16 = Wk16 + (size_t)NDIM * KDIM;
  _Float16* qraw = Wv16 + (size_t)NDIM * KDIM;
  _Float16* kraw = qraw + (size_t)MROWS * NDIM;
  float* rope_tab = (float*)(kraw + (size_t)MROWS * NDIM);  // 1 MiB, own region
  // total ws: 184 MiB + 1 MiB

  cvt7_kernel<<<dim3(2048, 1, 7), dim3(256), 0, stream>>>(
      q_state, k_state, v_state, Wq, Wk, Wv, Aq, Ak, Av, Wq16, Wk16, Wv16,
      offset, rope_tab);

  gemm_kernel<<<dim3(8, 32, 3), dim3(512), 0, stream>>>(
      Aq, Ak, Av, Wq16, Wk16, Wv16, qraw, kraw, vout);

  ln_rope_kernel<<<dim3(8192, 2), dim3(256), 0, stream>>>(
      qraw, kraw, negator, q_gamma, q_beta, k_gamma, k_beta, rope_tab, out);
}